// Round 3
// baseline (88.720 us; speedup 1.0000x reference)
//
#include <hip/hip_runtime.h>

// LSTMModel, T=16384 autonomous steps. IN=1 and h=c=0 at every cell call
// -> each step is a FIXED scalar map: pred[t+1] = F(pred[t]).
//
// R7 design: two kernels.
//  K1 (build, 257 blocks x 512 thr): 8 waves/block, one grid point per wave,
//     4 chained evals -> tables F^1..F^4 on a 2049-node grid over [-R, R],
//     R = sum|Wfc|+|bfc| (strict bound on |pred|), plus pred0 = F(batch[0]).
//     R6 failure: 2050 one-wave blocks each issued ~75 scattered 8B loads
//     (200B lane stride -> ~50 cache lines per instr -> ~7.7M L2 line
//     requests). Now each BLOCK stages the 3 live Wih1 slabs (3x2500 floats,
//     contiguous) into LDS with coalesced float4 loads (~60x less traffic),
//     and waves copy LDS->VGPR once.
//  K2 (sequential, 1 wave): tables as (A, dA) v2 pairs in LDS (64 KiB);
//     one lookup chain advances FOUR steps. Loop is ROTATED: next iter's
//     4x ds_read_b64 issue right after p4, so the exit-predicate fmin tree
//     + store run inside the ~120cy LDS latency shadow. Staging unroll 8.
//     Exit detection + period-2 tail fill semantically identical to R4/R6.
//
// Accuracy: delta = 2R/2048 ~ 4e-3 -> lerp err ~ delta^2*|F''|/8 ~ 1e-5
// per lookup, contraction-bounded accumulation << bf16 threshold (R5/R6
// passed with absmax 0.0). R/delta computed bit-identically in both kernels.

#define HID    50
#define TSTEPS 16384
#define NTAB   2048            // lerp intervals (delta = R * 2^-10, exact scale)
#define NNODE  (NTAB + 1)      // 2049 nodes per table
#define TAU    1e-6f
#define WPB    8               // waves (grid points) per K1 block

typedef float v2 __attribute__((ext_vector_type(2)));

__device__ __forceinline__ float fexp2(float x) { return __builtin_amdgcn_exp2f(x); }
__device__ __forceinline__ float frcp(float x)  { return __builtin_amdgcn_rcpf(x); }
// tanh(x) = 2/(1+2^(-2x*log2e)) - 1
__device__ __forceinline__ float tanh_(float x) { return fmaf(2.0f, frcp(1.0f + fexp2(-2.88539008177792681f * x)), -1.0f); }

// DPP wave64 sum -> total in lane 63 -> readlane (uniform result).
template <int CTRL, int RMASK>
__device__ __forceinline__ float dpp_add(float s) {
    int v = __builtin_amdgcn_update_dpp(0, __float_as_int(s), CTRL, RMASK, 0xf, true);
    return s + __int_as_float(v);
}
__device__ __forceinline__ float wave_sum_to_sgpr(float s) {
    s = dpp_add<0x111, 0xf>(s);  // row_shr:1
    s = dpp_add<0x112, 0xf>(s);  // row_shr:2
    s = dpp_add<0x114, 0xf>(s);  // row_shr:4
    s = dpp_add<0x118, 0xf>(s);  // row_shr:8
    s = dpp_add<0x142, 0xa>(s);  // row_bcast:15 -> rows 1,3
    s = dpp_add<0x143, 0xc>(s);  // row_bcast:31 -> rows 2,3
    return __int_as_float(__builtin_amdgcn_readlane(__float_as_int(s), 63));
}

// R = sum_j |Wfc[j]| + |bfc|  -- strict bound on |pred| (relu(h1) < 1).
// MUST be computed with identical code in both kernels (bitwise-equal R).
__device__ __forceinline__ float pred_range(const float* Wfc, const float* bfc, int lane) {
    float s = (lane < HID) ? fabsf(Wfc[lane]) : 0.0f;
    return wave_sum_to_sgpr(s) + fabsf(bfc[0]);
}

// ---------------------------------------------------------------------------
// K1: build tables. Grid = 257 blocks x 512 threads; task = blk*8 + wave.
//  task <= NTAB: x = -R + task*delta; chain y1..y4 = F..F^4(x);
//                tab[k*NNODE + task] = y_{k+1}
//  task == NNODE: tab[4*NNODE] = F(batch[0])   (pred0, exact)
//  task >  NNODE: compute (barrier lockstep), no store.
// ---------------------------------------------------------------------------
__global__ __launch_bounds__(64 * WPB, 2)
void lstm_build_tables(const float* __restrict__ batch,
                       const float* __restrict__ Wih0,
                       const float* __restrict__ bih0,
                       const float* __restrict__ bhh0,
                       const float* __restrict__ Wih1,
                       const float* __restrict__ bih1,
                       const float* __restrict__ bhh1,
                       const float* __restrict__ Wfc,
                       const float* __restrict__ bfc,
                       float* __restrict__ tab)
{
    // live Wih1 slabs: rows [0,50) / [100,150) / [150,200), 2500 floats each
    __shared__ alignas(16) float wlds[3 * 2500];
    __shared__ alignas(16) float h0s[WPB][64];

    const int tid  = threadIdx.x;
    const int lane = tid & 63;
    const int wv   = tid >> 6;
    const bool act = lane < HID;

    // ---- block-cooperative coalesced staging of Wih1 slabs ----
    {
        const float4* s4 = (const float4*)Wih1;     // slab f4 ranges: [0,625),
        float4*       d4 = (float4*)wlds;           // [1250,1875), [1875,2500)
        for (int i = tid; i < 3 * 625; i += 64 * WPB) {
            const int src = (i < 625) ? i : i + 625;
            d4[i] = s4[src];
        }
    }
    __syncthreads();

    const float NL2E  = -1.44269504088896341f;   // -log2(e)
    const float N2L2E = -2.88539008177792681f;   // -2*log2(e)

    // ---- per-lane weight copy LDS->VGPR (scale factors folded) ----
    v2 wI[HID / 2], wG[HID / 2], wO[HID / 2];
    float b1i = 0, b1g = 0, b1o = 0;
    float wi0 = 0, wg0 = 0, wo0 = 0, bi0 = 0, bg0 = 0, bo0 = 0, wfc = 0;
    if (act) {
        const v2* rI = (const v2*)(wlds +          lane * HID);
        const v2* rG = (const v2*)(wlds + 2500 +   lane * HID);
        const v2* rO = (const v2*)(wlds + 5000 +   lane * HID);
        #pragma unroll
        for (int q = 0; q < HID / 2; ++q) {
            wI[q] = rI[q] * NL2E;
            wG[q] = rG[q] * N2L2E;
            wO[q] = rO[q] * NL2E;
        }
        // lane-contiguous global loads (coalesced): biases + layer0 + fc
        b1i = NL2E  * (bih1[lane]       + bhh1[lane]);
        b1g = N2L2E * (bih1[100 + lane] + bhh1[100 + lane]);
        b1o = NL2E  * (bih1[150 + lane] + bhh1[150 + lane]);
        wi0 = NL2E  * Wih0[lane];       bi0 = NL2E  * (bih0[lane]       + bhh0[lane]);
        wg0 = N2L2E * Wih0[100 + lane]; bg0 = N2L2E * (bih0[100 + lane] + bhh0[100 + lane]);
        wo0 = NL2E  * Wih0[150 + lane]; bo0 = NL2E  * (bih0[150 + lane] + bhh0[150 + lane]);
        wfc = Wfc[lane];
    }
    const float bfcv = bfc[0];

    const float R     = pred_range(Wfc, bfc, lane);
    const float delta = R * (2.0f / NTAB);       // R * 2^-10, exact scale

    const int task = (int)blockIdx.x * WPB + wv;
    const int node = (task <= NTAB) ? task : NTAB;
    float y = (task == NNODE) ? batch[0] : fmaf((float)node, delta, -R);
    float ys[4];

    #pragma unroll 1
    for (int r = 0; r < 4; ++r) {
        // layer 0: scalar input, elementwise
        {
            float ei = fexp2(fmaf(y, wi0, bi0));
            float eg = fexp2(fmaf(y, wg0, bg0));
            float eo = fexp2(fmaf(y, wo0, bo0));
            float si = frcp(1.0f + ei);
            float tg = fmaf(2.0f, frcp(1.0f + eg), -1.0f);
            float so = frcp(1.0f + eo);
            float c  = si * tg;
            h0s[wv][lane] = so * tanh_(c);
        }
        __syncthreads();                         // lockstep: all waves, 4 iters
        // layer 1: three pre-scaled row-dots per lane
        float rr = 0.0f;
        if (act) {
            const float4* h4 = (const float4*)h0s[wv];
            v2 aI = {b1i, 0.0f}, aG = {b1g, 0.0f}, aO = {b1o, 0.0f};
            #pragma unroll
            for (int q = 0; q < 12; ++q) {
                float4 h = h4[q];
                v2 hlo = {h.x, h.y}, hhi = {h.z, h.w};
                aI += wI[2*q] * hlo;  aI += wI[2*q + 1] * hhi;
                aG += wG[2*q] * hlo;  aG += wG[2*q + 1] * hhi;
                aO += wO[2*q] * hlo;  aO += wO[2*q + 1] * hhi;
            }
            v2 ht = ((const v2*)h0s[wv])[24];
            aI += wI[24] * ht;  aG += wG[24] * ht;  aO += wO[24] * ht;
            float si = frcp(1.0f + fexp2(aI.x + aI.y));
            float tg = fmaf(2.0f, frcp(1.0f + fexp2(aG.x + aG.y)), -1.0f);
            float so = frcp(1.0f + fexp2(aO.x + aO.y));
            float c1 = si * tg;
            float h1 = so * tanh_(c1);
            rr = fmaxf(h1, 0.0f) * wfc;
        }
        const float pred = wave_sum_to_sgpr(rr) + bfcv;
        __syncthreads();                         // h0s reads done before rewrite
        ys[r] = pred;
        y = pred;
    }

    if (lane == 0) {
        if (task <= NTAB) {
            tab[            task] = ys[0];
            tab[    NNODE + task] = ys[1];
            tab[2 * NNODE + task] = ys[2];
            tab[3 * NNODE + task] = ys[3];
        } else if (task == NNODE) {
            tab[4 * NNODE] = ys[0];              // pred0 = F(batch[0])
        }
    }
}

// ---------------------------------------------------------------------------
// K2: sequential iteration via LDS lerp tables, 4 steps / lookup chain.
// Rotated loop: next lookups issue before the exit check (latency shadow).
// ---------------------------------------------------------------------------
__global__ __launch_bounds__(64, 1)
void lstm_iterate(const float* __restrict__ Wfc,
                  const float* __restrict__ bfc,
                  float* __restrict__ out)
{
    // 4 tables x 2048 x (A, dA) = 64 KiB exactly.
    __shared__ v2 T1[NTAB], T2[NTAB], T3[NTAB], T4[NTAB];
    const int lane = threadIdx.x;

    const float R     = pred_range(Wfc, bfc, lane);   // bitwise == K1's R
    const float delta = R * (2.0f / NTAB);
    const float invd  = 1.0f / delta;
    const float uoff  = R * invd;                     // u = p*invd + uoff

    // ---- stage tables from `out` into LDS as (A, dA) pairs ----
    const float* g1 = out;
    const float* g2 = out +     NNODE;
    const float* g3 = out + 2 * NNODE;
    const float* g4 = out + 3 * NNODE;
    #pragma unroll 8
    for (int v = 0; v < NTAB / 64; ++v) {
        const int idx = v * 64 + lane;
        const float a1 = g1[idx], n1 = g1[idx + 1];
        const float a2 = g2[idx], n2 = g2[idx + 1];
        const float a3 = g3[idx], n3 = g3[idx + 1];
        const float a4 = g4[idx], n4 = g4[idx + 1];
        v2 e1 = {a1, n1 - a1};  T1[idx] = e1;
        v2 e2 = {a2, n2 - a2};  T2[idx] = e2;
        v2 e3 = {a3, n3 - a3};  T3[idx] = e3;
        v2 e4 = {a4, n4 - a4};  T4[idx] = e4;
    }
    float p0 = out[4 * NNODE];                   // pred0 = F(batch[0]), exact
    __syncthreads();   // single wave: waitcnt; table reads retired before stores

    float pm1 = __int_as_float(0x7fc00000);      // pred[t-1] (NaN sentinel)

    // ---- prologue: first lookup ----
    float u = fmaf(p0, invd, uoff);
    int idx = (int)u;
    idx = idx < 0 ? 0 : (idx > NTAB - 1 ? NTAB - 1 : idx);
    float frac = u - (float)idx;
    v2 e1 = T1[idx], e2 = T2[idx], e3 = T3[idx], e4 = T4[idx];

    for (int t = 0; t < TSTEPS; t += 4) {
        const float p1 = fmaf(frac, e1.y, e1.x); // F(p0)
        const float p2 = fmaf(frac, e2.y, e2.x); // F^2(p0)
        const float p3 = fmaf(frac, e3.y, e3.x); // F^3(p0)
        const float p4 = fmaf(frac, e4.y, e4.x); // F^4(p0)

        // issue next-iteration lookups ASAP (speculative across exit check;
        // exit tree + store run inside the ds_read latency shadow)
        const float u2 = fmaf(p4, invd, uoff);
        int idx2 = (int)u2;
        idx2 = idx2 < 0 ? 0 : (idx2 > NTAB - 1 ? NTAB - 1 : idx2);
        const float frac2 = u2 - (float)idx2;
        const v2 f1 = T1[idx2], f2 = T2[idx2], f3 = T3[idx2], f4 = T4[idx2];

        // orbit detection at each sub-step (fmin ignores the NaN sentinel)
        const float d1 = fminf(fabsf(p1 - p0), fabsf(p1 - pm1));
        const float d2 = fminf(fabsf(p2 - p1), fabsf(p2 - p0));
        const float d3 = fminf(fabsf(p3 - p2), fabsf(p3 - p1));
        const float d4 = fminf(fabsf(p4 - p3), fabsf(p4 - p2));
        const float dm = fminf(fminf(d1, d2), fminf(d3, d4));

        if (dm <= TAU) {                         // wave-uniform, cold path
            int k; float pred, vodd;
            if      (d1 <= TAU) { k = 1; pred = p1; vodd = p0; }
            else if (d2 <= TAU) { k = 2; pred = p2; vodd = p1; }
            else if (d3 <= TAU) { k = 3; pred = p3; vodd = p2; }
            else                { k = 4; pred = p4; vodd = p3; }
            const int s = t + k;                 // exit step
            if (lane == 0) {                     // scalar head: out[t..s]
                out[t]     = p0;
                out[t + 1] = p1;
                if (k >= 2) out[t + 2] = p2;
                if (k >= 3) out[t + 3] = p3;
                if (k >= 4 && s < TSTEPS) out[t + 4] = p4;
            }
            // ---- period-2 tail fill (proven scheme), from s+1 ----
            const int base = s + 1;
            const int a4i  = (base + 3) & ~3;
            if (base + lane < a4i && base + lane < TSTEPS)
                out[base + lane] = (((base + lane - s) & 1) ? vodd : pred);
            if (a4i < TSTEPS) {
                const int par = (a4i - s) & 1;
                float4 P;
                P.x = par ? vodd : pred;  P.y = par ? pred : vodd;
                P.z = P.x;                P.w = P.y;
                float4* o4 = (float4*)out;
                for (int q = a4i / 4 + lane; q < TSTEPS / 4; q += 64)
                    o4[q] = P;                   // TSTEPS%4==0: no tail
            }
            return;
        }

        if (lane == 0) {                         // aligned, fire-and-forget
            float4 st; st.x = p0; st.y = p1; st.z = p2; st.w = p3;
            ((float4*)out)[t >> 2] = st;
        }
        pm1 = p3; p0 = p4; frac = frac2;
        e1 = f1; e2 = f2; e3 = f3; e4 = f4;
    }
}

extern "C" void kernel_launch(void* const* d_in, const int* in_sizes, int n_in,
                              void* d_out, int out_size, void* d_ws, size_t ws_size,
                              hipStream_t stream) {
    // setup_inputs order:
    // 0 batch, 1 Wih0, 2 Whh0(unused), 3 bih0, 4 bhh0,
    // 5 Wih1, 6 Whh1(unused), 7 bih1, 8 bhh1, 9 Wfc, 10 bfc
    const float* batch = (const float*)d_in[0];
    const float* Wih0  = (const float*)d_in[1];
    const float* bih0  = (const float*)d_in[3];
    const float* bhh0  = (const float*)d_in[4];
    const float* Wih1  = (const float*)d_in[5];
    const float* bih1  = (const float*)d_in[7];
    const float* bhh1  = (const float*)d_in[8];
    const float* Wfc   = (const float*)d_in[9];
    const float* bfc   = (const float*)d_in[10];
    float* out = (float*)d_out;

    // K1: parallel table build (8 points/block, LDS-staged weights).
    const int nblk = (NNODE + 1 + WPB - 1) / WPB;   // 257
    lstm_build_tables<<<nblk, 64 * WPB, 0, stream>>>(
        batch, Wih0, bih0, bhh0, Wih1, bih1, bhh1, Wfc, bfc, out);
    // K2: sequential lerp iteration, 4 steps per rotated lookup chain.
    lstm_iterate<<<1, 64, 0, stream>>>(Wfc, bfc, out);
}